// Round 14
// baseline (567.323 us; speedup 1.0000x reference)
//
#include <hip/hip_runtime.h>
#include <hip/hip_bf16.h>

namespace {

constexpr int NB = 4;          // batch
constexpr int CI = 2048;       // in channels
constexpr int CO = 1024;       // out channels
constexpr int HW = 4096;       // H*W
constexpr int MTOT = NB * HW;  // 16384 flattened rows

typedef __attribute__((ext_vector_type(8))) short bf16x8;
typedef __attribute__((ext_vector_type(4))) float f32x4;
typedef __hip_bfloat16 bf16;

__device__ __forceinline__ void g2l16(void* lds, const void* g) {
  __builtin_amdgcn_global_load_lds((const __attribute__((address_space(1))) void*)g,
                                   (__attribute__((address_space(3))) void*)lds,
                                   16, 0, 0);
}

__global__ void zero_k(float* __restrict__ p, int n) {
  int i = blockIdx.x * 256 + threadIdx.x;
  if (i < n) p[i] = 0.f;
}

// all six weight casts in one launch; y<3 are CI*CO, y>=3 are CO*CO; float4->ushort4
__global__ void castw6_k(const float* s0, const float* s1, const float* s2,
                         const float* s3, const float* s4, const float* s5,
                         bf16* d0, bf16* d1, bf16* d2, bf16* d3, bf16* d4, bf16* d5) {
  int y = blockIdx.y;
  const float* s = (y == 0) ? s0 : (y == 1) ? s1 : (y == 2) ? s2 : (y == 3) ? s3 : (y == 4) ? s4 : s5;
  bf16* d = (y == 0) ? d0 : (y == 1) ? d1 : (y == 2) ? d2 : (y == 3) ? d3 : (y == 4) ? d4 : d5;
  int n4 = ((y < 3) ? CI * CO : CO * CO) >> 2;
  int i = blockIdx.x * 256 + threadIdx.x;
  if (i < n4) {
    float4 v = ((const float4*)s)[i];
    union { ushort4 u; bf16 h[4]; } pk;
    pk.h[0] = __float2bfloat16(v.x);
    pk.h[1] = __float2bfloat16(v.y);
    pk.h[2] = __float2bfloat16(v.z);
    pk.h[3] = __float2bfloat16(v.w);
    ((ushort4*)d)[i] = pk.u;
  }
}

// dst[b,p4..p4+3] += sum over 128-channel chunk of src[b,c,p]; float4 loads.
// grid (HW/1024, CI/128, NB), block 256
__global__ void nc_sum_k(const float* __restrict__ src, float* __restrict__ dst) {
  int p4 = (blockIdx.x * 256 + threadIdx.x) * 4;
  int c0 = blockIdx.y * 128;
  int b = blockIdx.z;
  const float* s = src + ((long)b * CI + c0) * HW + p4;
  float4 a = make_float4(0.f, 0.f, 0.f, 0.f);
  #pragma unroll 4
  for (int c = 0; c < 128; ++c) {
    float4 v = *(const float4*)(s + (long)c * HW);
    a.x += v.x; a.y += v.y; a.z += v.z; a.w += v.w;
  }
  float* dp = dst + b * HW + p4;
  atomicAdd(dp + 0, a.x);
  atomicAdd(dp + 1, a.y);
  atomicAdd(dp + 2, a.z);
  atomicAdd(dp + 3, a.w);
}

// 64x64-tile float4 transpose: dst[b, s, r] = src[b, r, s]; grid (R/64, S/64, NB)
template <typename TO>
__global__ void transpose64_k(const float* __restrict__ src, TO* __restrict__ dst,
                              int R, int S) {
  __shared__ float tile[64][65];
  const int b = blockIdx.z;
  const int r0 = blockIdx.x * 64, s0 = blockIdx.y * 64;
  const int t = threadIdx.x;
  const int fc = t & 15;        // float4 column
  const int rr = t >> 4;        // 16 rows / pass
  const float* sp = src + ((size_t)b * R + r0) * S + s0;
  #pragma unroll
  for (int i = 0; i < 4; ++i) {
    float4 v = *(const float4*)(sp + (size_t)(rr + i * 16) * S + fc * 4);
    tile[rr + i * 16][fc * 4 + 0] = v.x;
    tile[rr + i * 16][fc * 4 + 1] = v.y;
    tile[rr + i * 16][fc * 4 + 2] = v.z;
    tile[rr + i * 16][fc * 4 + 3] = v.w;
  }
  __syncthreads();
  #pragma unroll
  for (int i = 0; i < 4; ++i) {
    const int sr = rr + i * 16;
    float4 w;
    w.x = tile[fc * 4 + 0][sr];
    w.y = tile[fc * 4 + 1][sr];
    w.z = tile[fc * 4 + 2][sr];
    w.w = tile[fc * 4 + 3][sr];
    if constexpr (sizeof(TO) == 4) {
      *(float4*)((float*)dst + ((size_t)b * S + s0 + sr) * R + r0 + fc * 4) = w;
    } else {
      union { ushort4 u; bf16 h[4]; } pk;
      pk.h[0] = __float2bfloat16(w.x);
      pk.h[1] = __float2bfloat16(w.y);
      pk.h[2] = __float2bfloat16(w.z);
      pk.h[3] = __float2bfloat16(w.w);
      *(ushort4*)((bf16*)dst + ((size_t)b * S + s0 + sr) * R + r0 + fc * 4) = pk.u;
    }
  }
}

// aligned (channels-last, bf16), with inlined 5x5 box denom (boxinv fused).
// One block per (b,p); threads cover c in float4.
__global__ void align_k(const float* __restrict__ pmcl, const float* __restrict__ nc,
                        const int* __restrict__ body, bf16* __restrict__ ah) {
  int bp = blockIdx.x;
  int b = bp >> 12, p = bp & 4095;
  int y = p >> 6, x = p & 63;
  int c = threadIdx.x * 4;
  float4 acc = make_float4(0.f, 0.f, 0.f, 0.f);
  if (body[0]) {
    float s25 = 0.f;
    #pragma unroll
    for (int dy = -2; dy <= 2; ++dy) {
      int yy = y + dy;
      if ((unsigned)yy >= 64u) continue;
      #pragma unroll
      for (int dx = -2; dx <= 2; ++dx) {
        int xx = x + dx;
        if ((unsigned)xx >= 64u) continue;
        int sp = yy * 64 + xx;
        float w = nc[b * HW + sp];
        s25 += w;
        float4 v = *(const float4*)(pmcl + ((long)b * HW + sp) * CO + c);
        acc.x += w * v.x; acc.y += w * v.y; acc.z += w * v.z; acc.w += w * v.w;
      }
    }
    float s = 1.f / (2048.f * s25);
    acc.x *= s; acc.y *= s; acc.z *= s; acc.w *= s;
  } else {
    acc = *(const float4*)(pmcl + (long)bp * CO + c);
  }
  union { ushort4 u; bf16 h[4]; } pk;
  pk.h[0] = __float2bfloat16(acc.x);
  pk.h[1] = __float2bfloat16(acc.y);
  pk.h[2] = __float2bfloat16(acc.z);
  pk.h[3] = __float2bfloat16(acc.w);
  *(ushort4*)(ah + (long)bp * CO + c) = pk.u;
}

// ---------------------------------------------------------------------------
// 256x256-tile dual-K GEMM — TWO-BLOCKS-PER-CU variant: BK=32, ring-2 of
// 32 KiB subtiles (64 KiB LDS total), __launch_bounds__(512) with NO
// occupancy demand (regs stay ~120+128 acc, well under the 2048/SIMD pool
// at 4 waves/SIMD) -> occupancy is LDS-bound at 2 blocks/CU. Two
// barrier-decorrelated blocks let one block's MFMAs overlap the other's
// LDS reads / staging (m114 mechanism) WITHOUT shrinking the tile (FETCH
// unchanged; R6's failure mode avoided) and WITHOUT a register cap (R10's
// failure mode avoided).
// Schedule per phase tp (R9-proven one-barrier order):
//   [vmcnt(0) drains stage tp (issued a full phase ago, ~free); barrier
//    (stage-tp writes visible; all waves consumed their phase-(tp-1) reads
//    of buf[(tp+1)&1]); STAGE(tp+1) -> other buffer; 12 ds_read_b128;
//    setprio + 32 MFMA + setprio]
// Swizzled LDS (0 conflicts, both-sides rule), XCD 2x2 remap (R13, counter-
// verified -2.5 us/dispatch).
// C[p,o] = sum_k A1[p,k]B1[o,k] + sum_k A2[p,k]B2[o,k];  K1=2048, K2=1024.
// MODE 0: zt[p,o]   = bf16(relu(acc + b1 + b2))              (bf16, chan-last)
// MODE 3: ar[p,o]   = bf16(aligh * relu(acc + b1 + b2))      (bf16, chan-last)
// MODE 2: m = relu(acc + b1 + b2);
//         out[b,o,p] = (1-zt)*aligh + zt*m                   (f32, chan-FIRST)
// ---------------------------------------------------------------------------
template <int MODE>
__global__ __launch_bounds__(512) void gemm256(
    const bf16* __restrict__ A1, const bf16* __restrict__ B1,
    const bf16* __restrict__ A2, const bf16* __restrict__ B2,
    const float* __restrict__ bias1, const float* __restrict__ bias2,
    const bf16* __restrict__ ztp, const bf16* __restrict__ aligh,
    bf16* __restrict__ outh, float* __restrict__ outcf) {
  constexpr int NT1 = CI / 32;        // 64
  constexpr int NT = NT1 + CO / 32;   // 96
  __shared__ __align__(16) char lds[65536];
  const int t = threadIdx.x, lane = t & 63, wid = t >> 6;
  const int wm = wid >> 2, wn = wid & 3;
  // --- XCD 2x2-aware remap: bid -> (rowp 0..63, colp 0..3) ---
  const int bid = blockIdx.x;
  const int xcd = bid & 7, j = bid >> 3;          // j 0..31
  const int colp = ((xcd >> 2) << 1) | (j & 1);   // XCD 0-3 -> cols {0,1}; 4-7 -> {2,3}
  const int rowp = ((xcd & 3) << 4) | (j >> 1);   // 16 row-panels per XCD
  const int m0 = rowp * 256, n0 = colp * 256;
  const int fr = lane & 15, kq = lane >> 4;

  // --- staging source precompute (inverse swizzle on global address) ---
  const int b0i = (wid << 7) + lane;
  const int line0 = b0i >> 3;
  const int c3 = (b0i & 7) ^ (line0 & 7);
  const int row0 = 2 * line0 + (c3 >> 2);
  const int k16 = c3 & 3;
  const char* pa1 = (const char*)A1 + (((size_t)(m0 + row0) * CI + k16 * 8) << 1);
  const char* pa1h = pa1 + ((size_t)CI << 5);   // +16 rows
  const char* pb1 = (const char*)B1 + (((size_t)(n0 + row0) * CI + k16 * 8) << 1);
  const char* pb1h = pb1 + ((size_t)CI << 5);
  const char* pa2 = (const char*)A2 + (((size_t)(m0 + row0) * CO + k16 * 8) << 1);
  const char* pa2h = pa2 + ((size_t)CO << 5);
  const char* pb2 = (const char*)B2 + (((size_t)(n0 + row0) * CO + k16 * 8) << 1);
  const char* pb2h = pb2 + ((size_t)CO << 5);

  auto STAGE = [&](int s) {
    const char *sa, *sah, *sb, *sbh;
    if (s < NT1) {
      size_t so = (size_t)s << 6;
      sa = pa1 + so; sah = pa1h + so; sb = pb1 + so; sbh = pb1h + so;
    } else {
      size_t so = (size_t)(s - NT1) << 6;
      sa = pa2 + so; sah = pa2h + so; sb = pb2 + so; sbh = pb2h + so;
    }
    char* d = lds + ((s & 1) << 15) + (wid << 11) + (lane << 4);
    g2l16(d, sa);
    g2l16(d + 1024, sah);
    g2l16(d + 16384, sb);
    g2l16(d + 17408, sbh);
  };

  // --- fragment LDS read offsets (swizzled), loop-invariant ---
  int offA[8], offB[4];
  #pragma unroll
  for (int mi = 0; mi < 8; ++mi) {
    int r = (wm << 7) + (mi << 4) + fr;
    int ln = r >> 1;
    int cc = ((r & 1) << 2) | kq;
    offA[mi] = (ln << 7) + ((cc ^ (ln & 7)) << 4);
  }
  #pragma unroll
  for (int ni = 0; ni < 4; ++ni) {
    int r = (wn << 6) + (ni << 4) + fr;
    int ln = r >> 1;
    int cc = ((r & 1) << 2) | kq;
    offB[ni] = 16384 + (ln << 7) + ((cc ^ (ln & 7)) << 4);
  }

  f32x4 acc[8][4] = {};

  STAGE(0);

  #pragma unroll 1
  for (int tp = 0; tp < NT; ++tp) {
    asm volatile("s_waitcnt vmcnt(0)" ::: "memory");   // stage tp retired (~free)
    __builtin_amdgcn_s_barrier();                      // writes visible; prior reads consumed
    asm volatile("" ::: "memory");
    if (tp + 1 < NT) STAGE(tp + 1);                    // -> other buffer, safe
    const char* buf = lds + ((tp & 1) << 15);
    bf16x8 av[8], bv[4];
    #pragma unroll
    for (int mi = 0; mi < 8; ++mi) av[mi] = *(const bf16x8*)(buf + offA[mi]);
    #pragma unroll
    for (int ni = 0; ni < 4; ++ni) bv[ni] = *(const bf16x8*)(buf + offB[ni]);
    __builtin_amdgcn_s_setprio(1);
    #pragma unroll
    for (int mi = 0; mi < 8; ++mi)
      #pragma unroll
      for (int ni = 0; ni < 4; ++ni)
        acc[mi][ni] = __builtin_amdgcn_mfma_f32_16x16x32_bf16(av[mi], bv[ni], acc[mi][ni], 0, 0, 0);
    __builtin_amdgcn_s_setprio(0);
    asm volatile("" ::: "memory");
  }

  // --- epilogue ---
  #pragma unroll
  for (int mi = 0; mi < 8; ++mi) {
    const int r0 = m0 + (wm << 7) + (mi << 4) + (kq << 2);
    #pragma unroll
    for (int ni = 0; ni < 4; ++ni) {
      const int col = n0 + (wn << 6) + (ni << 4) + fr;
      const float bsum = bias1[col] + bias2[col];
      if (MODE == 2) {
        // channels-first float4 write: 4 consecutive p at fixed (b, col)
        const int bb = r0 >> 12, p0 = r0 & 4095;
        float4 o;
        float* po = &o.x;
        #pragma unroll
        for (int j2 = 0; j2 < 4; ++j2) {
          const size_t idx = (size_t)(r0 + j2) * CO + col;
          float m = fmaxf(acc[mi][ni][j2] + bsum, 0.f);
          float z = __bfloat162float(ztp[idx]);
          float a = __bfloat162float(aligh[idx]);
          po[j2] = (1.f - z) * a + z * m;
        }
        *(float4*)(outcf + ((size_t)bb * CO + col) * HW + p0) = o;
      } else {
        #pragma unroll
        for (int j2 = 0; j2 < 4; ++j2) {
          const size_t idx = (size_t)(r0 + j2) * CO + col;
          float v = fmaxf(acc[mi][ni][j2] + bsum, 0.f);
          if (MODE == 0) {
            outh[idx] = __float2bfloat16(v);
          } else {  // MODE 3
            outh[idx] = __float2bfloat16(__bfloat162float(aligh[idx]) * v);
          }
        }
      }
    }
  }
}

}  // namespace

extern "C" void kernel_launch(void* const* d_in, const int* in_sizes, int n_in,
                              void* d_out, int out_size, void* d_ws, size_t ws_size,
                              hipStream_t stream) {
  const float* curr_F = (const float*)d_in[0];
  const float* prev_F = (const float*)d_in[1];
  const float* prev_M = (const float*)d_in[2];
  const float* Wz_w = (const float*)d_in[3];
  const float* Wz_b = (const float*)d_in[4];
  const float* Wr_w = (const float*)d_in[5];
  const float* Wr_b = (const float*)d_in[6];
  const float* W_w  = (const float*)d_in[7];
  const float* W_b  = (const float*)d_in[8];
  const float* Uz_w = (const float*)d_in[9];
  const float* Uz_b = (const float*)d_in[10];
  const float* Ur_w = (const float*)d_in[11];
  const float* Ur_b = (const float*)d_in[12];
  const float* U_w  = (const float*)d_in[13];
  const float* U_b  = (const float*)d_in[14];
  const int* body   = (const int*)d_in[15];
  float* out = (float*)d_out;

  char* ws = (char*)d_ws;
  const size_t M64 = 1ull << 26;  // 64 MiB
  const size_t M32 = 1ull << 25;  // 32 MiB
  // region0: currF bf16 cl (read-only through all GEMMs)
  bf16*  currF_h   = (bf16*)(ws);
  // region1: prevM f32 cl (dead after align_k) -> zt bf16 reuses its space
  float* prevM_cl  = (float*)(ws + M64);
  bf16*  zt        = (bf16*)(ws + M64);
  bf16*  align_h   = (bf16*)(ws + 2 * M64);
  bf16*  ar_h      = (bf16*)(ws + 2 * M64 + M32);
  char*  wb        = ws + 2 * M64 + 2 * M32;
  bf16* Wz_h = (bf16*)wb;
  bf16* Wr_h = Wz_h + (size_t)CO * CI;
  bf16* W_h  = Wr_h + (size_t)CO * CI;
  bf16* Uz_h = W_h  + (size_t)CO * CI;
  bf16* Ur_h = Uz_h + (size_t)CO * CO;
  bf16* U_h  = Ur_h + (size_t)CO * CO;
  float* prev_nc = (float*)(U_h + (size_t)CO * CO);

  // weights -> bf16 (one launch)
  castw6_k<<<dim3((CI * CO) / 1024, 6), 256, 0, stream>>>(
      Wz_w, Wr_w, W_w, Uz_w, Ur_w, U_w, Wz_h, Wr_h, W_h, Uz_h, Ur_h, U_h);

  // prev_nc = sum_c prev_F
  zero_k<<<dim3((NB * HW) / 256), 256, 0, stream>>>(prev_nc, NB * HW);
  nc_sum_k<<<dim3(HW / 1024, CI / 128, NB), 256, 0, stream>>>(prev_F, prev_nc);

  // transposes to channels-last (vectorized 64x64)
  transpose64_k<bf16><<<dim3(CI / 64, HW / 64, NB), 256, 0, stream>>>(curr_F, currF_h, CI, HW);
  transpose64_k<float><<<dim3(CO / 64, HW / 64, NB), 256, 0, stream>>>(prev_M, prevM_cl, CO, HW);

  // aligned (boxinv fused)
  align_k<<<dim3(NB * HW), 256, 0, stream>>>(prevM_cl, prev_nc, body, align_h);

  // 1D grid of 256 blocks; XCD 2x2-aware remap inside the kernel.
  dim3 gg(256);
  // zt = bf16(relu(Wz@curr + Uz@aligned + biases))   [bn_star is a no-op for B=4]
  gemm256<0><<<gg, 512, 0, stream>>>(currF_h, Wz_h, align_h, Uz_h,
                                     Wz_b, Uz_b, nullptr, nullptr, zt, nullptr);
  // ar = bf16(aligned * relu(Wr@curr + Ur@aligned + biases))
  gemm256<3><<<gg, 512, 0, stream>>>(currF_h, Wr_h, align_h, Ur_h,
                                     Wr_b, Ur_b, nullptr, align_h, ar_h, nullptr);
  // out[b,o,p] = (1-zt)*aligned + zt*relu(W@curr + U@ar + W_b + U_b)
  gemm256<2><<<gg, 512, 0, stream>>>(currF_h, W_h, ar_h, U_h,
                                     W_b, U_b, zt, align_h, nullptr, out);
}

// Round 15
// 512.663 us; speedup vs baseline: 1.1066x; 1.1066x over previous
//
#include <hip/hip_runtime.h>
#include <hip/hip_bf16.h>

namespace {

constexpr int NB = 4;          // batch
constexpr int CI = 2048;       // in channels
constexpr int CO = 1024;       // out channels
constexpr int HW = 4096;       // H*W
constexpr int MTOT = NB * HW;  // 16384 flattened rows

typedef __attribute__((ext_vector_type(8))) short bf16x8;
typedef __attribute__((ext_vector_type(4))) float f32x4;
typedef __hip_bfloat16 bf16;

__device__ __forceinline__ void g2l16(void* lds, const void* g) {
  __builtin_amdgcn_global_load_lds((const __attribute__((address_space(1))) void*)g,
                                   (__attribute__((address_space(3))) void*)lds,
                                   16, 0, 0);
}

__global__ void zero_k(float* __restrict__ p, int n) {
  int i = blockIdx.x * 256 + threadIdx.x;
  if (i < n) p[i] = 0.f;
}

// all six weight casts in one launch; y<3 are CI*CO, y>=3 are CO*CO; float4->ushort4
__global__ void castw6_k(const float* s0, const float* s1, const float* s2,
                         const float* s3, const float* s4, const float* s5,
                         bf16* d0, bf16* d1, bf16* d2, bf16* d3, bf16* d4, bf16* d5) {
  int y = blockIdx.y;
  const float* s = (y == 0) ? s0 : (y == 1) ? s1 : (y == 2) ? s2 : (y == 3) ? s3 : (y == 4) ? s4 : s5;
  bf16* d = (y == 0) ? d0 : (y == 1) ? d1 : (y == 2) ? d2 : (y == 3) ? d3 : (y == 4) ? d4 : d5;
  int n4 = ((y < 3) ? CI * CO : CO * CO) >> 2;
  int i = blockIdx.x * 256 + threadIdx.x;
  if (i < n4) {
    float4 v = ((const float4*)s)[i];
    union { ushort4 u; bf16 h[4]; } pk;
    pk.h[0] = __float2bfloat16(v.x);
    pk.h[1] = __float2bfloat16(v.y);
    pk.h[2] = __float2bfloat16(v.z);
    pk.h[3] = __float2bfloat16(v.w);
    ((ushort4*)d)[i] = pk.u;
  }
}

// dst[b,p4..p4+3] += sum over 128-channel chunk of src[b,c,p]; float4 loads.
// grid (HW/1024, CI/128, NB), block 256
__global__ void nc_sum_k(const float* __restrict__ src, float* __restrict__ dst) {
  int p4 = (blockIdx.x * 256 + threadIdx.x) * 4;
  int c0 = blockIdx.y * 128;
  int b = blockIdx.z;
  const float* s = src + ((long)b * CI + c0) * HW + p4;
  float4 a = make_float4(0.f, 0.f, 0.f, 0.f);
  #pragma unroll 4
  for (int c = 0; c < 128; ++c) {
    float4 v = *(const float4*)(s + (long)c * HW);
    a.x += v.x; a.y += v.y; a.z += v.z; a.w += v.w;
  }
  float* dp = dst + b * HW + p4;
  atomicAdd(dp + 0, a.x);
  atomicAdd(dp + 1, a.y);
  atomicAdd(dp + 2, a.z);
  atomicAdd(dp + 3, a.w);
}

// 64x64-tile float4 transpose: dst[b, s, r] = src[b, r, s]; grid (R/64, S/64, NB)
template <typename TO>
__global__ void transpose64_k(const float* __restrict__ src, TO* __restrict__ dst,
                              int R, int S) {
  __shared__ float tile[64][65];
  const int b = blockIdx.z;
  const int r0 = blockIdx.x * 64, s0 = blockIdx.y * 64;
  const int t = threadIdx.x;
  const int fc = t & 15;        // float4 column
  const int rr = t >> 4;        // 16 rows / pass
  const float* sp = src + ((size_t)b * R + r0) * S + s0;
  #pragma unroll
  for (int i = 0; i < 4; ++i) {
    float4 v = *(const float4*)(sp + (size_t)(rr + i * 16) * S + fc * 4);
    tile[rr + i * 16][fc * 4 + 0] = v.x;
    tile[rr + i * 16][fc * 4 + 1] = v.y;
    tile[rr + i * 16][fc * 4 + 2] = v.z;
    tile[rr + i * 16][fc * 4 + 3] = v.w;
  }
  __syncthreads();
  #pragma unroll
  for (int i = 0; i < 4; ++i) {
    const int sr = rr + i * 16;
    float4 w;
    w.x = tile[fc * 4 + 0][sr];
    w.y = tile[fc * 4 + 1][sr];
    w.z = tile[fc * 4 + 2][sr];
    w.w = tile[fc * 4 + 3][sr];
    if constexpr (sizeof(TO) == 4) {
      *(float4*)((float*)dst + ((size_t)b * S + s0 + sr) * R + r0 + fc * 4) = w;
    } else {
      union { ushort4 u; bf16 h[4]; } pk;
      pk.h[0] = __float2bfloat16(w.x);
      pk.h[1] = __float2bfloat16(w.y);
      pk.h[2] = __float2bfloat16(w.z);
      pk.h[3] = __float2bfloat16(w.w);
      *(ushort4*)((bf16*)dst + ((size_t)b * S + s0 + sr) * R + r0 + fc * 4) = pk.u;
    }
  }
}

// aligned (channels-last, bf16), with inlined 5x5 box denom (boxinv fused).
// One block per (b,p); threads cover c in float4.
__global__ void align_k(const float* __restrict__ pmcl, const float* __restrict__ nc,
                        const int* __restrict__ body, bf16* __restrict__ ah) {
  int bp = blockIdx.x;
  int b = bp >> 12, p = bp & 4095;
  int y = p >> 6, x = p & 63;
  int c = threadIdx.x * 4;
  float4 acc = make_float4(0.f, 0.f, 0.f, 0.f);
  if (body[0]) {
    float s25 = 0.f;
    #pragma unroll
    for (int dy = -2; dy <= 2; ++dy) {
      int yy = y + dy;
      if ((unsigned)yy >= 64u) continue;
      #pragma unroll
      for (int dx = -2; dx <= 2; ++dx) {
        int xx = x + dx;
        if ((unsigned)xx >= 64u) continue;
        int sp = yy * 64 + xx;
        float w = nc[b * HW + sp];
        s25 += w;
        float4 v = *(const float4*)(pmcl + ((long)b * HW + sp) * CO + c);
        acc.x += w * v.x; acc.y += w * v.y; acc.z += w * v.z; acc.w += w * v.w;
      }
    }
    float s = 1.f / (2048.f * s25);
    acc.x *= s; acc.y *= s; acc.z *= s; acc.w *= s;
  } else {
    acc = *(const float4*)(pmcl + (long)bp * CO + c);
  }
  union { ushort4 u; bf16 h[4]; } pk;
  pk.h[0] = __float2bfloat16(acc.x);
  pk.h[1] = __float2bfloat16(acc.y);
  pk.h[2] = __float2bfloat16(acc.z);
  pk.h[3] = __float2bfloat16(acc.w);
  *(ushort4*)(ah + (long)bp * CO + c) = pk.u;
}

// ---------------------------------------------------------------------------
// 256x256-tile dual-K GEMM — measured-best configuration (R13: gemm
// 119.6-121.3 us, MfmaUtil ~35, 0 bank conflicts): BK=32, ring-4 of 32 KiB
// subtiles, prefetch depth 2, ONE barrier per phase, counted vmcnt(8),
// zero-conflict swizzled LDS (both-sides rule), setprio, XCD 2x2 remap.
// Phase tp: [STAGE(tp+2) -> buf[(tp+2)&3] (safe: its reads finished before
// barrier(tp-1)); vmcnt(8) retires stage tp; barrier; 12 ds_read_b128;
// 32 MFMA].
// C[p,o] = sum_k A1[p,k]B1[o,k] + sum_k A2[p,k]B2[o,k];  K1=2048, K2=1024.
// MODE 0: zt[p,o]   = bf16(relu(acc + b1 + b2))              (bf16, chan-last)
// MODE 3: ar[p,o]   = bf16(aligh * relu(acc + b1 + b2))      (bf16, chan-last)
// MODE 2: m = relu(acc + b1 + b2);
//         out[b,o,p] = (1-zt)*aligh + zt*m                   (f32, chan-FIRST)
// ---------------------------------------------------------------------------
template <int MODE>
__global__ __launch_bounds__(512, 2) void gemm256(
    const bf16* __restrict__ A1, const bf16* __restrict__ B1,
    const bf16* __restrict__ A2, const bf16* __restrict__ B2,
    const float* __restrict__ bias1, const float* __restrict__ bias2,
    const bf16* __restrict__ ztp, const bf16* __restrict__ aligh,
    bf16* __restrict__ outh, float* __restrict__ outcf) {
  constexpr int NT1 = CI / 32;        // 64
  constexpr int NT = NT1 + CO / 32;   // 96
  __shared__ __align__(16) char lds[131072];
  const int t = threadIdx.x, lane = t & 63, wid = t >> 6;
  const int wm = wid >> 2, wn = wid & 3;
  // --- XCD 2x2-aware remap: bid -> (rowp 0..63, colp 0..3) ---
  const int bid = blockIdx.x;
  const int xcd = bid & 7, j = bid >> 3;          // j 0..31
  const int colp = ((xcd >> 2) << 1) | (j & 1);   // XCD 0-3 -> cols {0,1}; 4-7 -> {2,3}
  const int rowp = ((xcd & 3) << 4) | (j >> 1);   // 16 row-panels per XCD
  const int m0 = rowp * 256, n0 = colp * 256;
  const int fr = lane & 15, kq = lane >> 4;

  // --- staging source precompute (inverse swizzle on global address) ---
  const int b0i = (wid << 7) + lane;
  const int line0 = b0i >> 3;
  const int c3 = (b0i & 7) ^ (line0 & 7);
  const int row0 = 2 * line0 + (c3 >> 2);
  const int k16 = c3 & 3;
  const char* pa1 = (const char*)A1 + (((size_t)(m0 + row0) * CI + k16 * 8) << 1);
  const char* pa1h = pa1 + ((size_t)CI << 5);   // +16 rows
  const char* pb1 = (const char*)B1 + (((size_t)(n0 + row0) * CI + k16 * 8) << 1);
  const char* pb1h = pb1 + ((size_t)CI << 5);
  const char* pa2 = (const char*)A2 + (((size_t)(m0 + row0) * CO + k16 * 8) << 1);
  const char* pa2h = pa2 + ((size_t)CO << 5);
  const char* pb2 = (const char*)B2 + (((size_t)(n0 + row0) * CO + k16 * 8) << 1);
  const char* pb2h = pb2 + ((size_t)CO << 5);

  auto STAGE = [&](int s) {
    const char *sa, *sah, *sb, *sbh;
    if (s < NT1) {
      size_t so = (size_t)s << 6;
      sa = pa1 + so; sah = pa1h + so; sb = pb1 + so; sbh = pb1h + so;
    } else {
      size_t so = (size_t)(s - NT1) << 6;
      sa = pa2 + so; sah = pa2h + so; sb = pb2 + so; sbh = pb2h + so;
    }
    char* d = lds + ((s & 3) << 15) + (wid << 11) + (lane << 4);
    g2l16(d, sa);
    g2l16(d + 1024, sah);
    g2l16(d + 16384, sb);
    g2l16(d + 17408, sbh);
  };

  // --- fragment LDS read offsets (swizzled), loop-invariant ---
  int offA[8], offB[4];
  #pragma unroll
  for (int mi = 0; mi < 8; ++mi) {
    int r = (wm << 7) + (mi << 4) + fr;
    int ln = r >> 1;
    int cc = ((r & 1) << 2) | kq;
    offA[mi] = (ln << 7) + ((cc ^ (ln & 7)) << 4);
  }
  #pragma unroll
  for (int ni = 0; ni < 4; ++ni) {
    int r = (wn << 6) + (ni << 4) + fr;
    int ln = r >> 1;
    int cc = ((r & 1) << 2) | kq;
    offB[ni] = 16384 + (ln << 7) + ((cc ^ (ln & 7)) << 4);
  }

  f32x4 acc[8][4] = {};

  STAGE(0); STAGE(1);

  #pragma unroll 1
  for (int tp = 0; tp < NT; ++tp) {
    if (tp + 2 < NT) {
      STAGE(tp + 2);                                       // -> buf[(tp+2)&3], safe
      asm volatile("s_waitcnt vmcnt(8)" ::: "memory");     // retire stage tp
    } else if (tp + 1 < NT) {
      asm volatile("s_waitcnt vmcnt(4)" ::: "memory");
    } else {
      asm volatile("s_waitcnt vmcnt(0)" ::: "memory");
    }
    __builtin_amdgcn_s_barrier();                          // all waves' tp loads visible
    asm volatile("" ::: "memory");
    const char* buf = lds + ((tp & 3) << 15);
    bf16x8 av[8], bv[4];
    #pragma unroll
    for (int mi = 0; mi < 8; ++mi) av[mi] = *(const bf16x8*)(buf + offA[mi]);
    #pragma unroll
    for (int ni = 0; ni < 4; ++ni) bv[ni] = *(const bf16x8*)(buf + offB[ni]);
    __builtin_amdgcn_s_setprio(1);
    #pragma unroll
    for (int mi = 0; mi < 8; ++mi)
      #pragma unroll
      for (int ni = 0; ni < 4; ++ni)
        acc[mi][ni] = __builtin_amdgcn_mfma_f32_16x16x32_bf16(av[mi], bv[ni], acc[mi][ni], 0, 0, 0);
    __builtin_amdgcn_s_setprio(0);
    asm volatile("" ::: "memory");
  }

  // --- epilogue ---
  #pragma unroll
  for (int mi = 0; mi < 8; ++mi) {
    const int r0 = m0 + (wm << 7) + (mi << 4) + (kq << 2);
    #pragma unroll
    for (int ni = 0; ni < 4; ++ni) {
      const int col = n0 + (wn << 6) + (ni << 4) + fr;
      const float bsum = bias1[col] + bias2[col];
      if (MODE == 2) {
        // channels-first float4 write: 4 consecutive p at fixed (b, col)
        const int bb = r0 >> 12, p0 = r0 & 4095;
        float4 o;
        float* po = &o.x;
        #pragma unroll
        for (int j2 = 0; j2 < 4; ++j2) {
          const size_t idx = (size_t)(r0 + j2) * CO + col;
          float m = fmaxf(acc[mi][ni][j2] + bsum, 0.f);
          float z = __bfloat162float(ztp[idx]);
          float a = __bfloat162float(aligh[idx]);
          po[j2] = (1.f - z) * a + z * m;
        }
        *(float4*)(outcf + ((size_t)bb * CO + col) * HW + p0) = o;
      } else {
        #pragma unroll
        for (int j2 = 0; j2 < 4; ++j2) {
          const size_t idx = (size_t)(r0 + j2) * CO + col;
          float v = fmaxf(acc[mi][ni][j2] + bsum, 0.f);
          if (MODE == 0) {
            outh[idx] = __float2bfloat16(v);
          } else {  // MODE 3
            outh[idx] = __float2bfloat16(__bfloat162float(aligh[idx]) * v);
          }
        }
      }
    }
  }
}

}  // namespace

extern "C" void kernel_launch(void* const* d_in, const int* in_sizes, int n_in,
                              void* d_out, int out_size, void* d_ws, size_t ws_size,
                              hipStream_t stream) {
  const float* curr_F = (const float*)d_in[0];
  const float* prev_F = (const float*)d_in[1];
  const float* prev_M = (const float*)d_in[2];
  const float* Wz_w = (const float*)d_in[3];
  const float* Wz_b = (const float*)d_in[4];
  const float* Wr_w = (const float*)d_in[5];
  const float* Wr_b = (const float*)d_in[6];
  const float* W_w  = (const float*)d_in[7];
  const float* W_b  = (const float*)d_in[8];
  const float* Uz_w = (const float*)d_in[9];
  const float* Uz_b = (const float*)d_in[10];
  const float* Ur_w = (const float*)d_in[11];
  const float* Ur_b = (const float*)d_in[12];
  const float* U_w  = (const float*)d_in[13];
  const float* U_b  = (const float*)d_in[14];
  const int* body   = (const int*)d_in[15];
  float* out = (float*)d_out;

  char* ws = (char*)d_ws;
  const size_t M64 = 1ull << 26;  // 64 MiB
  const size_t M32 = 1ull << 25;  // 32 MiB
  // region0: currF bf16 cl (read-only through all GEMMs)
  bf16*  currF_h   = (bf16*)(ws);
  // region1: prevM f32 cl (dead after align_k) -> zt bf16 reuses its space
  float* prevM_cl  = (float*)(ws + M64);
  bf16*  zt        = (bf16*)(ws + M64);
  bf16*  align_h   = (bf16*)(ws + 2 * M64);
  bf16*  ar_h      = (bf16*)(ws + 2 * M64 + M32);
  char*  wb        = ws + 2 * M64 + 2 * M32;
  bf16* Wz_h = (bf16*)wb;
  bf16* Wr_h = Wz_h + (size_t)CO * CI;
  bf16* W_h  = Wr_h + (size_t)CO * CI;
  bf16* Uz_h = W_h  + (size_t)CO * CI;
  bf16* Ur_h = Uz_h + (size_t)CO * CO;
  bf16* U_h  = Ur_h + (size_t)CO * CO;
  float* prev_nc = (float*)(U_h + (size_t)CO * CO);

  // weights -> bf16 (one launch)
  castw6_k<<<dim3((CI * CO) / 1024, 6), 256, 0, stream>>>(
      Wz_w, Wr_w, W_w, Uz_w, Ur_w, U_w, Wz_h, Wr_h, W_h, Uz_h, Ur_h, U_h);

  // prev_nc = sum_c prev_F
  zero_k<<<dim3((NB * HW) / 256), 256, 0, stream>>>(prev_nc, NB * HW);
  nc_sum_k<<<dim3(HW / 1024, CI / 128, NB), 256, 0, stream>>>(prev_F, prev_nc);

  // transposes to channels-last (vectorized 64x64)
  transpose64_k<bf16><<<dim3(CI / 64, HW / 64, NB), 256, 0, stream>>>(curr_F, currF_h, CI, HW);
  transpose64_k<float><<<dim3(CO / 64, HW / 64, NB), 256, 0, stream>>>(prev_M, prevM_cl, CO, HW);

  // aligned (boxinv fused)
  align_k<<<dim3(NB * HW), 256, 0, stream>>>(prevM_cl, prev_nc, body, align_h);

  // 1D grid of 256 blocks; XCD 2x2-aware remap inside the kernel.
  dim3 gg(256);
  // zt = bf16(relu(Wz@curr + Uz@aligned + biases))   [bn_star is a no-op for B=4]
  gemm256<0><<<gg, 512, 0, stream>>>(currF_h, Wz_h, align_h, Uz_h,
                                     Wz_b, Uz_b, nullptr, nullptr, zt, nullptr);
  // ar = bf16(aligned * relu(Wr@curr + Ur@aligned + biases))
  gemm256<3><<<gg, 512, 0, stream>>>(currF_h, Wr_h, align_h, Ur_h,
                                     Wr_b, Ur_b, nullptr, align_h, ar_h, nullptr);
  // out[b,o,p] = (1-zt)*aligned + zt*relu(W@curr + U@ar + W_b + U_b)
  gemm256<2><<<gg, 512, 0, stream>>>(currF_h, W_h, ar_h, U_h,
                                     W_b, U_b, zt, align_h, nullptr, out);
}